// Round 10
// baseline (7870.267 us; speedup 1.0000x reference)
//
#include <hip/hip_runtime.h>
#include <cstdint>

#define NE 8
#define NEX 9
#define NTOK 16384
#define DDIM 1024
#define HDIM 2816

typedef unsigned short u16;
typedef __attribute__((ext_vector_type(8))) short short8;
typedef __attribute__((ext_vector_type(4))) float f32x4;

__device__ __forceinline__ u16 f2bf(float f) {
  uint32_t u = __builtin_bit_cast(uint32_t, f);
  u += 0x7FFFu + ((u >> 16) & 1u);
  return (u16)(u >> 16);
}

__device__ __forceinline__ float wave_reduce_sum(float v) {
  for (int off = 32; off > 0; off >>= 1) v += __shfl_xor(v, off, 64);
  return v;
}

#define GLOAD16(gsrc, ldst)                                                   \
  __builtin_amdgcn_global_load_lds(                                           \
      (const __attribute__((address_space(1))) unsigned int*)(gsrc),          \
      (__attribute__((address_space(3))) unsigned int*)(ldst), 16, 0, 0)

// bijective XCD-aware remap (m204), proven rounds 4/6/7/8
__device__ __forceinline__ void xcd_map(int NT, int MT, int* nt, int* mt) {
  int lin = blockIdx.y * NT + blockIdx.x;
  int nwg = NT * MT;
  int q = nwg >> 3, r = nwg & 7;
  int xcd = lin & 7, idx = lin >> 3;
  int nl = (xcd < r) ? (xcd * (q + 1) + idx) : (r * (q + 1) + (xcd - r) * q + idx);
  *nt = nl / MT;
  *mt = nl % MT;
}

// ---------------- init ----------------
__global__ void init_kernel(int* cnt, float* Pacc, float* fcnt) {
  int t = threadIdx.x;
  if (t < NEX) cnt[t] = (t == 8) ? NTOK : 0;
  if (t < NE) { Pacc[t] = 0.f; fcnt[t] = 0.f; }
}

// ---------------- fp32 -> bf16 convert ----------------
struct CvtArgs {
  const float* src[7];
  u16* dst[7];
  long long cum[8];
};

__global__ void convert_kernel(CvtArgs a) {
  long long stride = (long long)gridDim.x * blockDim.x;
  long long total = a.cum[7];
  for (long long g = (long long)blockIdx.x * blockDim.x + threadIdx.x; g < total; g += stride) {
    int s = 0;
    while (g >= a.cum[s + 1]) s++;
    long long off = (g - a.cum[s]) * 4;
    float4 v = *reinterpret_cast<const float4*>(a.src[s] + off);
    union { u16 u[4]; uint2 w; } o;
    o.u[0] = f2bf(v.x); o.u[1] = f2bf(v.y); o.u[2] = f2bf(v.z); o.u[3] = f2bf(v.w);
    *reinterpret_cast<uint2*>(a.dst[s] + off) = o.w;
  }
}

// ---------------- router (fp32 logits, exact top-k; also emits xbf) ----------
__global__ __launch_bounds__(256) void router_kernel(
    const float* __restrict__ x, const float* __restrict__ gw,
    int* __restrict__ tok, float* __restrict__ wtl,
    int* __restrict__ cnt, float* __restrict__ Pacc, float* __restrict__ fcnt,
    u16* __restrict__ xbf) {
  int lane = threadIdx.x & 63;
  int wv = threadIdx.x >> 6;
  __shared__ float red[4][16];
  float pP[NE], pF[NE];
#pragma unroll
  for (int e = 0; e < NE; e++) { pP[e] = 0.f; pF[e] = 0.f; }
  int t0 = blockIdx.x * 16 + wv * 4;
  for (int ti = 0; ti < 4; ti++) {
    int t = t0 + ti;
    float part[NE];
#pragma unroll
    for (int e = 0; e < NE; e++) part[e] = 0.f;
    const float* xp = x + (size_t)t * DDIM;
#pragma unroll
    for (int j = 0; j < 16; j++) {
      float xv = xp[lane + j * 64];
      xbf[(size_t)t * DDIM + lane + j * 64] = f2bf(xv);  // fused convert
#pragma unroll
      for (int e = 0; e < NE; e++) part[e] += xv * gw[e * DDIM + lane + j * 64];
    }
#pragma unroll
    for (int e = 0; e < NE; e++) part[e] = wave_reduce_sum(part[e]);
    if (lane == 0) {
      float v0 = -1e30f, v1 = -1e30f; int i0 = 0, i1 = 0;
#pragma unroll
      for (int e = 0; e < NE; e++) {
        float v = part[e];
        if (v > v0) { v1 = v0; i1 = i0; v0 = v; i0 = e; }
        else if (v > v1) { v1 = v; i1 = e; }
      }
      float e1 = expf(v1 - v0);
      float w0 = 1.f / (1.f + e1);
      float w1 = e1 * w0;
      float s = 0.f, g[NE];
#pragma unroll
      for (int e = 0; e < NE; e++) { g[e] = expf(part[e] - v0); s += g[e]; }
      float inv = 1.f / s;
#pragma unroll
      for (int e = 0; e < NE; e++) pP[e] += g[e] * inv;
      pF[i0] += 1.f;
      int p0 = atomicAdd(&cnt[i0], 1);
      tok[i0 * NTOK + p0] = t; wtl[i0 * NTOK + p0] = w0;
      int p1 = atomicAdd(&cnt[i1], 1);
      tok[i1 * NTOK + p1] = t; wtl[i1 * NTOK + p1] = w1;
      tok[8 * NTOK + t] = t; wtl[8 * NTOK + t] = 1.f;
    }
  }
  if (lane == 0) {
#pragma unroll
    for (int e = 0; e < NE; e++) { red[wv][e] = pP[e]; red[wv][e + 8] = pF[e]; }
  }
  __syncthreads();
  if (threadIdx.x < 16) {
    float s = red[0][threadIdx.x] + red[1][threadIdx.x] + red[2][threadIdx.x] + red[3][threadIdx.x];
    if (threadIdx.x < 8) atomicAdd(&Pacc[threadIdx.x], s);
    else atomicAdd(&fcnt[threadIdx.x - 8], s);
  }
}

// ---------------- finalize: global slot offsets + aux loss ----------------
__global__ void finalize_router(const int* cnt, int* offs, const float* Pacc,
                                const float* fcnt, float* out_aux) {
  if (threadIdx.x == 0 && blockIdx.x == 0) {
    int p = NTOK;
    for (int e = 0; e < NE; e++) { offs[e] = p; p += cnt[e]; }
    offs[8] = 0;
    float aux = 0.f;
    for (int e = 0; e < NE; e++)
      aux += (fcnt[e] * (1.f / NTOK)) * (Pacc[e] * (1.f / NTOK));
    *out_aux = 0.01f * 8.f * aux;
  }
}

// LDS XOR swizzle (tile rows x [8 chunks of 8 u16]):
//   physical_chunk = logical_chunk ^ (row & 7)
// gload_lds stage: lane l writes phys chunk l&7 of row with row&7==l>>3
//   -> pre-swizzled global source chunk (l&7)^(l>>3).
// frag read: logical chunk kk*4+(lane>>4), row&7==lane&7 -> phys ^(lane&7).

// ========== tier F/G wide kernels: BM=256, 512 thr, 8 waves, single-buffer ===

// pass1w: LDS 64KB (X 32 + G 16 + U 16) -> 2 blocks/CU = 16 waves/CU.
__global__ __launch_bounds__(512, 4) void pass1w_kernel(
    const u16* __restrict__ xbf, const u16* __restrict__ WGall,
    const u16* __restrict__ WUall, const u16* __restrict__ SG,
    const u16* __restrict__ SU, const int* __restrict__ tok,
    const int* __restrict__ cnt, const int* __restrict__ offs,
    u16* __restrict__ Abuf, int e0, int ab_off) {
  int nt, mt;
  xcd_map(gridDim.x, gridDim.y, &nt, &mt);
  int e = e0 + blockIdx.z;
  int Me = cnt[e];
  if (mt * 256 >= Me) return;
  int base = offs[e];

  __shared__ u16 lX[256 * 64];
  __shared__ u16 lG[128 * 64];
  __shared__ u16 lU[128 * 64];

  int tid = threadIdx.x, lane = tid & 63, wv = tid >> 6;
  int wm = wv >> 1, wn = wv & 1;
  size_t wst = (size_t)HDIM * DDIM;
  int swsrc = ((lane & 7) ^ (lane >> 3)) * 8;

  const u16* gx[4];
#pragma unroll
  for (int q = 0; q < 4; q++) {
    int r = (wv * 4 + q) * 8 + (lane >> 3);        // 0..255
    int gm = mt * 256 + r;
    int tk = (gm < Me) ? tok[e * NTOK + gm] : 0;
    gx[q] = xbf + (size_t)tk * DDIM + swsrc;
  }
  const u16* G = (e == 8) ? SG : WGall + (size_t)e * wst;
  const u16* U = (e == 8) ? SU : WUall + (size_t)e * wst;
  const u16 *gg[2], *gu[2];
#pragma unroll
  for (int q = 0; q < 2; q++) {
    int r = (wv * 2 + q) * 8 + (lane >> 3);        // 0..127
    gg[q] = G + (size_t)(nt * 128 + r) * DDIM + swsrc;
    gu[q] = U + (size_t)(nt * 128 + r) * DDIM + swsrc;
  }

  f32x4 accG[4][4] = {};
  f32x4 accU[4][4] = {};

  for (int kt = 0; kt < DDIM / 64; kt++) {
    __syncthreads();
    int ko = kt * 64;
#pragma unroll
    for (int q = 0; q < 4; q++)
      GLOAD16(gx[q] + ko, lX + (wv * 4 + q) * 512);
#pragma unroll
    for (int q = 0; q < 2; q++) {
      GLOAD16(gg[q] + ko, lG + (wv * 2 + q) * 512);
      GLOAD16(gu[q] + ko, lU + (wv * 2 + q) * 512);
    }
    asm volatile("s_waitcnt vmcnt(0)" ::: "memory");
    __syncthreads();

#pragma unroll
    for (int kk = 0; kk < 2; kk++) {
      int kbs = ((kk * 4 + (lane >> 4)) ^ (lane & 7)) * 8;
      short8 af[4];
#pragma unroll
      for (int m = 0; m < 4; m++) {
        int row = wm * 64 + m * 16 + (lane & 15);
        af[m] = *reinterpret_cast<const short8*>(lX + row * 64 + kbs);
      }
#pragma unroll
      for (int n = 0; n < 4; n++) {
        int hr = wn * 64 + n * 16 + (lane & 15);
        short8 bg = *reinterpret_cast<const short8*>(lG + hr * 64 + kbs);
        short8 bu = *reinterpret_cast<const short8*>(lU + hr * 64 + kbs);
#pragma unroll
        for (int m = 0; m < 4; m++) {
          accG[m][n] = __builtin_amdgcn_mfma_f32_16x16x32_bf16(af[m], bg, accG[m][n], 0, 0, 0);
          accU[m][n] = __builtin_amdgcn_mfma_f32_16x16x32_bf16(af[m], bu, accU[m][n], 0, 0, 0);
        }
      }
    }
  }

  int rsub = (lane >> 4) * 4, csub = lane & 15;
#pragma unroll
  for (int m = 0; m < 4; m++) {
#pragma unroll
    for (int i = 0; i < 4; i++) {
      int row = wm * 64 + m * 16 + rsub + i;
      int gm = mt * 256 + row;
      if (gm < Me) {
        size_t rb = (size_t)(base + gm - ab_off) * HDIM + nt * 128;
#pragma unroll
        for (int n = 0; n < 4; n++) {
          float hg = accG[m][n][i];
          float hu = accU[m][n][i];
          float a = 0.5f * hg * (1.f + erff(hg * 0.70710678118f)) * hu;
          Abuf[rb + wn * 64 + n * 16 + csub] = f2bf(a);
        }
      }
    }
  }
}

// pass2w: LDS 48KB (A 32 + B 16) -> 3 blocks/CU = 24 waves/CU.
__global__ __launch_bounds__(512, 6) void pass2w_kernel(
    const u16* __restrict__ Abuf, const u16* __restrict__ WDall,
    const u16* __restrict__ SD, const int* __restrict__ tok,
    const float* __restrict__ wtl, const int* __restrict__ cnt,
    const int* __restrict__ offs, float* __restrict__ out, int e0, int ab_off) {
  int nt, mt;
  xcd_map(gridDim.x, gridDim.y, &nt, &mt);
  int e = e0 + blockIdx.z;
  int Me = cnt[e];
  if (mt * 256 >= Me) return;
  int base = offs[e];
  size_t wst = (size_t)HDIM * DDIM;

  __shared__ u16 lA[256 * 64];
  __shared__ u16 lB[128 * 64];

  int tid = threadIdx.x, lane = tid & 63, wv = tid >> 6;
  int wm = wv >> 1, wn = wv & 1;
  int swsrc = ((lane & 7) ^ (lane >> 3)) * 8;

  const u16* ga[4];
#pragma unroll
  for (int q = 0; q < 4; q++) {
    int r = (wv * 4 + q) * 8 + (lane >> 3);        // 0..255
    int slot = base + mt * 256 + r - ab_off;       // overrun feeds masked rows only
    ga[q] = Abuf + (size_t)slot * HDIM + swsrc;
  }
  const u16* D = (e == 8) ? SD : WDall + (size_t)e * wst;
  const u16* gb[2];
#pragma unroll
  for (int q = 0; q < 2; q++) {
    int r = (wv * 2 + q) * 8 + (lane >> 3);        // 0..127
    gb[q] = D + (size_t)(nt * 128 + r) * HDIM + swsrc;
  }

  f32x4 acc[4][4] = {};

  for (int kt = 0; kt < HDIM / 64; kt++) {
    __syncthreads();
    int ko = kt * 64;
#pragma unroll
    for (int q = 0; q < 4; q++)
      GLOAD16(ga[q] + ko, lA + (wv * 4 + q) * 512);
#pragma unroll
    for (int q = 0; q < 2; q++)
      GLOAD16(gb[q] + ko, lB + (wv * 2 + q) * 512);
    asm volatile("s_waitcnt vmcnt(0)" ::: "memory");
    __syncthreads();

#pragma unroll
    for (int kk = 0; kk < 2; kk++) {
      int kbs = ((kk * 4 + (lane >> 4)) ^ (lane & 7)) * 8;
      short8 af[4];
#pragma unroll
      for (int m = 0; m < 4; m++) {
        int row = wm * 64 + m * 16 + (lane & 15);
        af[m] = *reinterpret_cast<const short8*>(lA + row * 64 + kbs);
      }
#pragma unroll
      for (int n = 0; n < 4; n++) {
        int dr = wn * 64 + n * 16 + (lane & 15);
        short8 bd = *reinterpret_cast<const short8*>(lB + dr * 64 + kbs);
#pragma unroll
        for (int m = 0; m < 4; m++)
          acc[m][n] = __builtin_amdgcn_mfma_f32_16x16x32_bf16(af[m], bd, acc[m][n], 0, 0, 0);
      }
    }
  }

  int rsub = (lane >> 4) * 4, csub = lane & 15;
#pragma unroll
  for (int m = 0; m < 4; m++) {
#pragma unroll
    for (int i = 0; i < 4; i++) {
      int row = wm * 64 + m * 16 + rsub + i;
      int gm = mt * 256 + row;
      if (gm < Me) {
        int t = tok[e * NTOK + gm];
        float w = (e == 8) ? 1.f : wtl[e * NTOK + gm];
        size_t ob = (size_t)t * DDIM + nt * 128;
#pragma unroll
        for (int n = 0; n < 4; n++) {
          float v = w * acc[m][n][i];
          int c = wn * 64 + n * 16 + csub;
          if (e == 8) out[ob + c] = out[ob + c] + v;  // runs last; 1 thread/elem
          else atomicAdd(&out[ob + c], v);
        }
      }
    }
  }
}

// ================= tier E/D legacy kernels (round-8 verbatim, fp32 staging) ===

__global__ __launch_bounds__(256, 2) void pass1_kernel(
    const u16* __restrict__ xbf, const float* __restrict__ WGall,
    const float* __restrict__ WUall, const float* __restrict__ SG,
    const float* __restrict__ SU, const int* __restrict__ tok,
    const int* __restrict__ cnt, const int* __restrict__ offs,
    u16* __restrict__ Abuf, int e0, int ab_off) {
  int nt, mt;
  xcd_map(gridDim.x, gridDim.y, &nt, &mt);
  int e = e0 + blockIdx.z;
  int Me = cnt[e];
  if (mt * 128 >= Me) return;
  int base = offs[e];
  int ab = (ab_off < 0) ? base : ab_off;

  __shared__ u16 lX[128 * 64];
  __shared__ u16 lG[128 * 64];
  __shared__ u16 lU[128 * 64];

  int tid = threadIdx.x, lane = tid & 63, wv = tid >> 6;
  int wr = wv >> 1, wc = wv & 1;
  size_t wst = (size_t)HDIM * DDIM;
  int swsrc = ((lane & 7) ^ (lane >> 3)) * 8;

  const u16* gx[4];
#pragma unroll
  for (int q = 0; q < 4; q++) {
    int r = (wv * 4 + q) * 8 + (lane >> 3);
    int gm = mt * 128 + r;
    int tk = (gm < Me) ? tok[e * NTOK + gm] : 0;
    gx[q] = xbf + (size_t)tk * DDIM + swsrc;
  }
  const float* G = (e == 8) ? SG : WGall + (size_t)e * wst;
  const float* U = (e == 8) ? SU : WUall + (size_t)e * wst;
  int st_r0 = wv * 32 + (lane >> 4);
  int c0 = (lane & 15) * 4;
  int st_chunk = c0 >> 3, st_win = c0 & 7;
  const float* pg0 = G + (size_t)(nt * 128 + st_r0) * DDIM + c0;
  const float* pu0 = U + (size_t)(nt * 128 + st_r0) * DDIM + c0;

  f32x4 accG[4][4] = {};
  f32x4 accU[4][4] = {};

  for (int kt = 0; kt < DDIM / 64; kt++) {
    __syncthreads();
    int ko = kt * 64;
#pragma unroll
    for (int q = 0; q < 4; q++)
      GLOAD16(gx[q] + ko, lX + (wv * 4 + q) * 512);
#pragma unroll
    for (int q = 0; q < 8; q++) {
      int row = st_r0 + q * 4;
      int pc = (((st_chunk ^ (row & 7)) << 3) | st_win);
      float4 vg = *reinterpret_cast<const float4*>(pg0 + ko + q * 4 * DDIM);
      float4 vu = *reinterpret_cast<const float4*>(pu0 + ko + q * 4 * DDIM);
      union { u16 h[4]; uint2 w; } og, ou;
      og.h[0] = f2bf(vg.x); og.h[1] = f2bf(vg.y); og.h[2] = f2bf(vg.z); og.h[3] = f2bf(vg.w);
      ou.h[0] = f2bf(vu.x); ou.h[1] = f2bf(vu.y); ou.h[2] = f2bf(vu.z); ou.h[3] = f2bf(vu.w);
      *reinterpret_cast<uint2*>(lG + row * 64 + pc) = og.w;
      *reinterpret_cast<uint2*>(lU + row * 64 + pc) = ou.w;
    }
    asm volatile("s_waitcnt vmcnt(0)" ::: "memory");
    __syncthreads();

#pragma unroll
    for (int kk = 0; kk < 2; kk++) {
      int kbs = (((kk * 4 + (lane >> 4)) ^ (lane & 7))) * 8;
      short8 af[4];
#pragma unroll
      for (int m = 0; m < 4; m++) {
        int row = wr * 64 + m * 16 + (lane & 15);
        af[m] = *reinterpret_cast<const short8*>(lX + row * 64 + kbs);
      }
#pragma unroll
      for (int n = 0; n < 4; n++) {
        int hr = wc * 64 + n * 16 + (lane & 15);
        short8 bg = *reinterpret_cast<const short8*>(lG + hr * 64 + kbs);
        short8 bu = *reinterpret_cast<const short8*>(lU + hr * 64 + kbs);
#pragma unroll
        for (int m = 0; m < 4; m++) {
          accG[m][n] = __builtin_amdgcn_mfma_f32_16x16x32_bf16(af[m], bg, accG[m][n], 0, 0, 0);
          accU[m][n] = __builtin_amdgcn_mfma_f32_16x16x32_bf16(af[m], bu, accU[m][n], 0, 0, 0);
        }
      }
    }
  }

  int rsub = (lane >> 4) * 4, csub = lane & 15;
#pragma unroll
  for (int m = 0; m < 4; m++) {
#pragma unroll
    for (int i = 0; i < 4; i++) {
      int row = wr * 64 + m * 16 + rsub + i;
      int gm = mt * 128 + row;
      if (gm < Me) {
        size_t rb = (size_t)(base + gm - ab) * HDIM + nt * 128;
#pragma unroll
        for (int n = 0; n < 4; n++) {
          float hg = accG[m][n][i];
          float hu = accU[m][n][i];
          float a = 0.5f * hg * (1.f + erff(hg * 0.70710678118f)) * hu;
          Abuf[rb + wc * 64 + n * 16 + csub] = f2bf(a);
        }
      }
    }
  }
}

__global__ __launch_bounds__(256, 2) void pass2_kernel(
    const u16* __restrict__ Abuf, const float* __restrict__ WDall,
    const float* __restrict__ SD, const int* __restrict__ tok,
    const float* __restrict__ wtl, const int* __restrict__ cnt,
    const int* __restrict__ offs, float* __restrict__ out, int e0, int ab_off) {
  int nt, mt;
  xcd_map(gridDim.x, gridDim.y, &nt, &mt);
  int e = e0 + blockIdx.z;
  int Me = cnt[e];
  if (mt * 128 >= Me) return;
  int base = offs[e];
  int ab = (ab_off < 0) ? base : ab_off;
  size_t wst = (size_t)HDIM * DDIM;

  __shared__ u16 lA[128 * 64];
  __shared__ u16 lB[128 * 64];

  int tid = threadIdx.x, lane = tid & 63, wv = tid >> 6;
  int wr = wv >> 1, wc = wv & 1;
  int swsrc = ((lane & 7) ^ (lane >> 3)) * 8;

  const u16* ga[4];
#pragma unroll
  for (int q = 0; q < 4; q++) {
    int r = (wv * 4 + q) * 8 + (lane >> 3);
    int slot = base + mt * 128 + r - ab;
    ga[q] = Abuf + (size_t)slot * HDIM + swsrc;
  }
  const float* D = (e == 8) ? SD : WDall + (size_t)e * wst;
  int st_r0 = wv * 32 + (lane >> 4);
  int c0 = (lane & 15) * 4;
  int st_chunk = c0 >> 3, st_win = c0 & 7;
  const float* pd0 = D + (size_t)(nt * 128 + st_r0) * HDIM + c0;

  f32x4 acc[4][4] = {};

  for (int kt = 0; kt < HDIM / 64; kt++) {
    __syncthreads();
    int ko = kt * 64;
#pragma unroll
    for (int q = 0; q < 4; q++)
      GLOAD16(ga[q] + ko, lA + (wv * 4 + q) * 512);
#pragma unroll
    for (int q = 0; q < 8; q++) {
      int row = st_r0 + q * 4;
      int pc = (((st_chunk ^ (row & 7)) << 3) | st_win);
      float4 vd = *reinterpret_cast<const float4*>(pd0 + ko + q * 4 * HDIM);
      union { u16 h[4]; uint2 w; } od;
      od.h[0] = f2bf(vd.x); od.h[1] = f2bf(vd.y); od.h[2] = f2bf(vd.z); od.h[3] = f2bf(vd.w);
      *reinterpret_cast<uint2*>(lB + row * 64 + pc) = od.w;
    }
    asm volatile("s_waitcnt vmcnt(0)" ::: "memory");
    __syncthreads();

#pragma unroll
    for (int kk = 0; kk < 2; kk++) {
      int kbs = (((kk * 4 + (lane >> 4)) ^ (lane & 7))) * 8;
      short8 af[4];
#pragma unroll
      for (int m = 0; m < 4; m++) {
        int row = wr * 64 + m * 16 + (lane & 15);
        af[m] = *reinterpret_cast<const short8*>(lA + row * 64 + kbs);
      }
#pragma unroll
      for (int n = 0; n < 4; n++) {
        int dr = wc * 64 + n * 16 + (lane & 15);
        short8 bd = *reinterpret_cast<const short8*>(lB + dr * 64 + kbs);
#pragma unroll
        for (int m = 0; m < 4; m++)
          acc[m][n] = __builtin_amdgcn_mfma_f32_16x16x32_bf16(af[m], bd, acc[m][n], 0, 0, 0);
      }
    }
  }

  int rsub = (lane >> 4) * 4, csub = lane & 15;
#pragma unroll
  for (int m = 0; m < 4; m++) {
#pragma unroll
    for (int i = 0; i < 4; i++) {
      int row = wr * 64 + m * 16 + rsub + i;
      int gm = mt * 128 + row;
      if (gm < Me) {
        int t = tok[e * NTOK + gm];
        float w = (e == 8) ? 1.f : wtl[e * NTOK + gm];
        size_t ob = (size_t)t * DDIM + nt * 128;
#pragma unroll
        for (int n = 0; n < 4; n++) {
          float v = w * acc[m][n][i];
          int c = wc * 64 + n * 16 + csub;
          if (e == 8) out[ob + c] = out[ob + c] + v;
          else atomicAdd(&out[ob + c], v);
        }
      }
    }
  }
}

// ---------------- host launcher ----------------
extern "C" void kernel_launch(void* const* d_in, const int* in_sizes, int n_in,
                              void* d_out, int out_size, void* d_ws, size_t ws_size,
                              hipStream_t stream) {
  const float* x  = (const float*)d_in[0];
  const float* gw = (const float*)d_in[1];
  const float* wg = (const float*)d_in[2];
  const float* wu = (const float*)d_in[3];
  const float* wd = (const float*)d_in[4];
  const float* sg = (const float*)d_in[5];
  const float* su = (const float*)d_in[6];
  const float* sd = (const float*)d_in[7];
  float* out = (float*)d_out;

  // Tier G >= 382 MB: all-bf16, wd/sd separate bufs, single convert.
  // Tier F >= 327 MB: all-bf16, wd/sd overlay dead wg/wu region (r8-proven).
  // Tier E >= 223 MB: fp32-staged weights.  Tier D: serial per-expert.
  bool tierG = ws_size >= 382000000ULL;
  bool tierF = !tierG && ws_size >= 327000000ULL;
  bool tierE = !tierG && !tierF && ws_size >= 223000000ULL;
  bool wide = tierG || tierF;

  char* ws = (char*)d_ws;
  size_t o = 0;
  auto alloc = [&](size_t bytes) -> void* {
    void* p = ws + o;
    o = (o + bytes + 255) & ~(size_t)255;
    return p;
  };
  u16* xbf = (u16*)alloc((size_t)NTOK * DDIM * 2);
  u16 *wgbf = nullptr, *wubf = nullptr, *sgbf = nullptr, *subf = nullptr;
  u16 *wdbf = nullptr, *sdbf = nullptr;
  if (wide) {
    wgbf = (u16*)alloc((size_t)NE * HDIM * DDIM * 2);
    wubf = (u16*)alloc((size_t)NE * HDIM * DDIM * 2);
    sgbf = (u16*)alloc((size_t)HDIM * DDIM * 2);
    subf = (u16*)alloc((size_t)HDIM * DDIM * 2);
    if (tierG) {
      wdbf = (u16*)alloc((size_t)NE * DDIM * HDIM * 2);
      sdbf = (u16*)alloc((size_t)DDIM * HDIM * 2);
    } else {
      wdbf = wgbf;                                  // overlay after p1-routed
      sdbf = wgbf + (size_t)NE * DDIM * HDIM;
    }
  }
  size_t abuf_rows = (wide || tierE) ? ((size_t)2 * NTOK + 256) : ((size_t)NTOK + 256);
  u16* Abuf = (u16*)alloc(abuf_rows * HDIM * 2);
  int*   tok  = (int*)alloc((size_t)NEX * NTOK * 4);
  float* wtl  = (float*)alloc((size_t)NEX * NTOK * 4);
  int*   cnt  = (int*)alloc(64);
  int*   offs = (int*)alloc(64);
  float* Pacc = (float*)alloc(64);
  float* fcnt = (float*)alloc(64);

  hipMemsetAsync(d_out, 0, (size_t)out_size * 4, stream);
  init_kernel<<<1, 64, 0, stream>>>(cnt, Pacc, fcnt);

  if (wide) {  // weight convert (x is fused into router)
    CvtArgs ca;
    long long sizes4[7];
    int nsrc = 0;
    ca.src[nsrc] = wg; ca.dst[nsrc] = wgbf; sizes4[nsrc] = (long long)NE * HDIM * DDIM / 4; nsrc++;
    ca.src[nsrc] = wu; ca.dst[nsrc] = wubf; sizes4[nsrc] = (long long)NE * HDIM * DDIM / 4; nsrc++;
    ca.src[nsrc] = sg; ca.dst[nsrc] = sgbf; sizes4[nsrc] = (long long)HDIM * DDIM / 4; nsrc++;
    ca.src[nsrc] = su; ca.dst[nsrc] = subf; sizes4[nsrc] = (long long)HDIM * DDIM / 4; nsrc++;
    if (tierG) {
      ca.src[nsrc] = wd; ca.dst[nsrc] = wdbf; sizes4[nsrc] = (long long)NE * DDIM * HDIM / 4; nsrc++;
      ca.src[nsrc] = sd; ca.dst[nsrc] = sdbf; sizes4[nsrc] = (long long)DDIM * HDIM / 4; nsrc++;
    }
    ca.cum[0] = 0;
    for (int i = 0; i < 7; i++)
      ca.cum[i + 1] = ca.cum[i] + (i < nsrc ? sizes4[i] : 0);
    convert_kernel<<<4096, 256, 0, stream>>>(ca);
  }

  router_kernel<<<NTOK / 16, 256, 0, stream>>>(x, gw, tok, wtl, cnt, Pacc, fcnt, xbf);
  finalize_router<<<1, 64, 0, stream>>>(cnt, offs, Pacc, fcnt, out + (out_size - 1));

  if (wide) {
    // routed-first full-bf16 schedule (BM=256 wide kernels)
    pass1w_kernel<<<dim3(HDIM / 128, NTOK / 256, NE), 512, 0, stream>>>(
        xbf, wgbf, wubf, sgbf, subf, tok, cnt, offs, Abuf, 0, NTOK);
    if (!tierG) {  // wg/wu dead -> convert wd,sd into their region
      CvtArgs ca;
      ca.src[0] = wd; ca.dst[0] = wdbf;
      ca.src[1] = sd; ca.dst[1] = sdbf;
      long long s0 = (long long)NE * DDIM * HDIM / 4;
      long long s1 = (long long)DDIM * HDIM / 4;
      ca.cum[0] = 0; ca.cum[1] = s0; ca.cum[2] = s0 + s1;
      for (int i = 3; i <= 7; i++) ca.cum[i] = ca.cum[2];
      convert_kernel<<<4096, 256, 0, stream>>>(ca);
    }
    pass2w_kernel<<<dim3(DDIM / 128, NTOK / 256, NE), 512, 0, stream>>>(
        Abuf, wdbf, sdbf, tok, wtl, cnt, offs, out, 0, NTOK);
    pass1w_kernel<<<dim3(HDIM / 128, NTOK / 256, 1), 512, 0, stream>>>(
        xbf, wgbf, wubf, sgbf, subf, tok, cnt, offs, Abuf, 8, 0);
    pass2w_kernel<<<dim3(DDIM / 128, NTOK / 256, 1), 512, 0, stream>>>(
        Abuf, wdbf, sdbf, tok, wtl, cnt, offs, out, 8, 0);
  } else if (tierE) {
    pass1_kernel<<<dim3(HDIM / 128, NTOK / 128, 1), 256, 0, stream>>>(
        xbf, wg, wu, sg, su, tok, cnt, offs, Abuf, 8, 0);
    pass2_kernel<<<dim3(DDIM / 128, NTOK / 128, 1), 256, 0, stream>>>(
        Abuf, wd, sd, tok, wtl, cnt, offs, out, 8, 0);
    pass1_kernel<<<dim3(HDIM / 128, NTOK / 128, NE), 256, 0, stream>>>(
        xbf, wg, wu, sg, su, tok, cnt, offs, Abuf, 0, NTOK);
    pass2_kernel<<<dim3(DDIM / 128, NTOK / 128, NE), 256, 0, stream>>>(
        Abuf, wd, sd, tok, wtl, cnt, offs, out, 0, NTOK);
  } else {
    for (int k = 0; k < NEX; k++) {
      int e = (k == 0) ? 8 : (k - 1);
      pass1_kernel<<<dim3(HDIM / 128, NTOK / 128, 1), 256, 0, stream>>>(
          xbf, wg, wu, sg, su, tok, cnt, offs, Abuf, e, -1);
      pass2_kernel<<<dim3(DDIM / 128, NTOK / 128, 1), 256, 0, stream>>>(
          Abuf, wd, sd, tok, wtl, cnt, offs, out, e, -1);
    }
  }
}

// Round 11
// 1667.809 us; speedup vs baseline: 4.7189x; 4.7189x over previous
//
#include <hip/hip_runtime.h>
#include <cstdint>

#define NE 8
#define NEX 9
#define NTOK 16384
#define DDIM 1024
#define HDIM 2816

typedef unsigned short u16;
typedef __attribute__((ext_vector_type(8))) short short8;
typedef __attribute__((ext_vector_type(4))) float f32x4;

__device__ __forceinline__ u16 f2bf(float f) {
  uint32_t u = __builtin_bit_cast(uint32_t, f);
  u += 0x7FFFu + ((u >> 16) & 1u);
  return (u16)(u >> 16);
}

__device__ __forceinline__ float wave_reduce_sum(float v) {
  for (int off = 32; off > 0; off >>= 1) v += __shfl_xor(v, off, 64);
  return v;
}

#define GLOAD16(gsrc, ldst)                                                   \
  __builtin_amdgcn_global_load_lds(                                           \
      (const __attribute__((address_space(1))) unsigned int*)(gsrc),          \
      (__attribute__((address_space(3))) unsigned int*)(ldst), 16, 0, 0)

// bijective XCD-aware remap (m204), proven rounds 4/6/7/8
__device__ __forceinline__ void xcd_map(int NT, int MT, int* nt, int* mt) {
  int lin = blockIdx.y * NT + blockIdx.x;
  int nwg = NT * MT;
  int q = nwg >> 3, r = nwg & 7;
  int xcd = lin & 7, idx = lin >> 3;
  int nl = (xcd < r) ? (xcd * (q + 1) + idx) : (r * (q + 1) + (xcd - r) * q + idx);
  *nt = nl / MT;
  *mt = nl % MT;
}

// ---------------- init ----------------
__global__ void init_kernel(int* cnt, float* Pacc, float* fcnt) {
  int t = threadIdx.x;
  if (t < NEX) cnt[t] = (t == 8) ? NTOK : 0;
  if (t < NE) { Pacc[t] = 0.f; fcnt[t] = 0.f; }
}

// ---------------- fp32 -> bf16 convert ----------------
struct CvtArgs {
  const float* src[7];
  u16* dst[7];
  long long cum[8];
};

__global__ void convert_kernel(CvtArgs a) {
  long long stride = (long long)gridDim.x * blockDim.x;
  long long total = a.cum[7];
  for (long long g = (long long)blockIdx.x * blockDim.x + threadIdx.x; g < total; g += stride) {
    int s = 0;
    while (g >= a.cum[s + 1]) s++;
    long long off = (g - a.cum[s]) * 4;
    float4 v = *reinterpret_cast<const float4*>(a.src[s] + off);
    union { u16 u[4]; uint2 w; } o;
    o.u[0] = f2bf(v.x); o.u[1] = f2bf(v.y); o.u[2] = f2bf(v.z); o.u[3] = f2bf(v.w);
    *reinterpret_cast<uint2*>(a.dst[s] + off) = o.w;
  }
}

// ---------------- router (fp32 logits, exact top-k; also emits xbf) ----------
__global__ __launch_bounds__(256) void router_kernel(
    const float* __restrict__ x, const float* __restrict__ gw,
    int* __restrict__ tok, float* __restrict__ wtl,
    int* __restrict__ cnt, float* __restrict__ Pacc, float* __restrict__ fcnt,
    u16* __restrict__ xbf) {
  int lane = threadIdx.x & 63;
  int wv = threadIdx.x >> 6;
  __shared__ float red[4][16];
  float pP[NE], pF[NE];
#pragma unroll
  for (int e = 0; e < NE; e++) { pP[e] = 0.f; pF[e] = 0.f; }
  int t0 = blockIdx.x * 16 + wv * 4;
  for (int ti = 0; ti < 4; ti++) {
    int t = t0 + ti;
    float part[NE];
#pragma unroll
    for (int e = 0; e < NE; e++) part[e] = 0.f;
    const float* xp = x + (size_t)t * DDIM;
#pragma unroll
    for (int j = 0; j < 16; j++) {
      float xv = xp[lane + j * 64];
      xbf[(size_t)t * DDIM + lane + j * 64] = f2bf(xv);  // fused convert (r10-proven)
#pragma unroll
      for (int e = 0; e < NE; e++) part[e] += xv * gw[e * DDIM + lane + j * 64];
    }
#pragma unroll
    for (int e = 0; e < NE; e++) part[e] = wave_reduce_sum(part[e]);
    if (lane == 0) {
      float v0 = -1e30f, v1 = -1e30f; int i0 = 0, i1 = 0;
#pragma unroll
      for (int e = 0; e < NE; e++) {
        float v = part[e];
        if (v > v0) { v1 = v0; i1 = i0; v0 = v; i0 = e; }
        else if (v > v1) { v1 = v; i1 = e; }
      }
      float e1 = expf(v1 - v0);
      float w0 = 1.f / (1.f + e1);
      float w1 = e1 * w0;
      float s = 0.f, g[NE];
#pragma unroll
      for (int e = 0; e < NE; e++) { g[e] = expf(part[e] - v0); s += g[e]; }
      float inv = 1.f / s;
#pragma unroll
      for (int e = 0; e < NE; e++) pP[e] += g[e] * inv;
      pF[i0] += 1.f;
      int p0 = atomicAdd(&cnt[i0], 1);
      tok[i0 * NTOK + p0] = t; wtl[i0 * NTOK + p0] = w0;
      int p1 = atomicAdd(&cnt[i1], 1);
      tok[i1 * NTOK + p1] = t; wtl[i1 * NTOK + p1] = w1;
      tok[8 * NTOK + t] = t; wtl[8 * NTOK + t] = 1.f;
    }
  }
  if (lane == 0) {
#pragma unroll
    for (int e = 0; e < NE; e++) { red[wv][e] = pP[e]; red[wv][e + 8] = pF[e]; }
  }
  __syncthreads();
  if (threadIdx.x < 16) {
    float s = red[0][threadIdx.x] + red[1][threadIdx.x] + red[2][threadIdx.x] + red[3][threadIdx.x];
    if (threadIdx.x < 8) atomicAdd(&Pacc[threadIdx.x], s);
    else atomicAdd(&fcnt[threadIdx.x - 8], s);
  }
}

// ---------------- finalize: global slot offsets + aux loss ----------------
__global__ void finalize_router(const int* cnt, int* offs, const float* Pacc,
                                const float* fcnt, float* out_aux) {
  if (threadIdx.x == 0 && blockIdx.x == 0) {
    int p = NTOK;
    for (int e = 0; e < NE; e++) { offs[e] = p; p += cnt[e]; }
    offs[8] = 0;
    float aux = 0.f;
    for (int e = 0; e < NE; e++)
      aux += (fcnt[e] * (1.f / NTOK)) * (Pacc[e] * (1.f / NTOK));
    *out_aux = 0.01f * 8.f * aux;
  }
}

// LDS XOR swizzle (tile rows x [8 chunks of 8 u16]):
//   physical_chunk = logical_chunk ^ (row & 7)
// gload_lds stage: lane l writes phys chunk l&7 of row with row&7==l>>3
//   -> pre-swizzled global source chunk (l&7)^(l>>3).
// frag read: logical chunk kk*4+(lane>>4), row&7==lane&7 -> phys ^(lane&7).

// ---------------- pass 1: A = gelu(X Wg^T) * (X Wu^T), bf16 out ----------------
// Round-8 verbatim (proven 1687 us total, MfmaUtil 29.6%, conflicts 0).
template<bool WB>
__global__ __launch_bounds__(256, 2) void pass1_kernel(
    const u16* __restrict__ xbf, const void* __restrict__ WGall,
    const void* __restrict__ WUall, const void* __restrict__ SG,
    const void* __restrict__ SU, const int* __restrict__ tok,
    const int* __restrict__ cnt, const int* __restrict__ offs,
    u16* __restrict__ Abuf, int e0, int ab_off) {
  int nt, mt;
  xcd_map(gridDim.x, gridDim.y, &nt, &mt);
  int e = e0 + blockIdx.z;
  int Me = cnt[e];
  if (mt * 128 >= Me) return;
  int base = offs[e];
  int ab = (ab_off < 0) ? base : ab_off;

  __shared__ u16 lX[128 * 64];
  __shared__ u16 lG[128 * 64];
  __shared__ u16 lU[128 * 64];

  int tid = threadIdx.x, lane = tid & 63, wv = tid >> 6;
  int wr = wv >> 1, wc = wv & 1;
  size_t wst = (size_t)HDIM * DDIM;
  int swsrc = ((lane & 7) ^ (lane >> 3)) * 8;

  const u16* gx[4];
#pragma unroll
  for (int q = 0; q < 4; q++) {
    int r = (wv * 4 + q) * 8 + (lane >> 3);
    int gm = mt * 128 + r;
    int tk = (gm < Me) ? tok[e * NTOK + gm] : 0;
    gx[q] = xbf + (size_t)tk * DDIM + swsrc;
  }

  const u16 *gg[4], *gu[4];
  const float *pg0 = nullptr, *pu0 = nullptr;
  int st_r0 = 0, st_chunk = 0, st_win = 0;
  if constexpr (WB) {
    const u16* G = (e == 8) ? (const u16*)SG : (const u16*)WGall + (size_t)e * wst;
    const u16* U = (e == 8) ? (const u16*)SU : (const u16*)WUall + (size_t)e * wst;
#pragma unroll
    for (int q = 0; q < 4; q++) {
      int r = (wv * 4 + q) * 8 + (lane >> 3);
      gg[q] = G + (size_t)(nt * 128 + r) * DDIM + swsrc;
      gu[q] = U + (size_t)(nt * 128 + r) * DDIM + swsrc;
    }
  } else {
    const float* G = (e == 8) ? (const float*)SG : (const float*)WGall + (size_t)e * wst;
    const float* U = (e == 8) ? (const float*)SU : (const float*)WUall + (size_t)e * wst;
    st_r0 = wv * 32 + (lane >> 4);
    int c0 = (lane & 15) * 4;
    st_chunk = c0 >> 3; st_win = c0 & 7;
    pg0 = G + (size_t)(nt * 128 + st_r0) * DDIM + c0;
    pu0 = U + (size_t)(nt * 128 + st_r0) * DDIM + c0;
  }

  f32x4 accG[4][4] = {};
  f32x4 accU[4][4] = {};

  for (int kt = 0; kt < DDIM / 64; kt++) {
    __syncthreads();
    int ko = kt * 64;
#pragma unroll
    for (int q = 0; q < 4; q++)
      GLOAD16(gx[q] + ko, lX + (wv * 4 + q) * 512);
    if constexpr (WB) {
#pragma unroll
      for (int q = 0; q < 4; q++) {
        int ldsoff = (wv * 4 + q) * 512;
        GLOAD16(gg[q] + ko, lG + ldsoff);
        GLOAD16(gu[q] + ko, lU + ldsoff);
      }
    } else {
#pragma unroll
      for (int q = 0; q < 8; q++) {
        int row = st_r0 + q * 4;
        int pc = (((st_chunk ^ (row & 7)) << 3) | st_win);
        float4 vg = *reinterpret_cast<const float4*>(pg0 + ko + q * 4 * DDIM);
        float4 vu = *reinterpret_cast<const float4*>(pu0 + ko + q * 4 * DDIM);
        union { u16 h[4]; uint2 w; } og, ou;
        og.h[0] = f2bf(vg.x); og.h[1] = f2bf(vg.y); og.h[2] = f2bf(vg.z); og.h[3] = f2bf(vg.w);
        ou.h[0] = f2bf(vu.x); ou.h[1] = f2bf(vu.y); ou.h[2] = f2bf(vu.z); ou.h[3] = f2bf(vu.w);
        *reinterpret_cast<uint2*>(lG + row * 64 + pc) = og.w;
        *reinterpret_cast<uint2*>(lU + row * 64 + pc) = ou.w;
      }
    }
    asm volatile("s_waitcnt vmcnt(0)" ::: "memory");
    __syncthreads();

    __builtin_amdgcn_s_setprio(1);
#pragma unroll
    for (int kk = 0; kk < 2; kk++) {
      int kbs = (((kk * 4 + (lane >> 4)) ^ (lane & 7))) * 8;
      short8 af[4];
#pragma unroll
      for (int m = 0; m < 4; m++) {
        int row = wr * 64 + m * 16 + (lane & 15);
        af[m] = *reinterpret_cast<const short8*>(lX + row * 64 + kbs);
      }
#pragma unroll
      for (int n = 0; n < 4; n++) {
        int hr = wc * 64 + n * 16 + (lane & 15);
        short8 bg = *reinterpret_cast<const short8*>(lG + hr * 64 + kbs);
        short8 bu = *reinterpret_cast<const short8*>(lU + hr * 64 + kbs);
#pragma unroll
        for (int m = 0; m < 4; m++) {
          accG[m][n] = __builtin_amdgcn_mfma_f32_16x16x32_bf16(af[m], bg, accG[m][n], 0, 0, 0);
          accU[m][n] = __builtin_amdgcn_mfma_f32_16x16x32_bf16(af[m], bu, accU[m][n], 0, 0, 0);
        }
      }
    }
    __builtin_amdgcn_s_setprio(0);
  }

  int rsub = (lane >> 4) * 4, csub = lane & 15;
#pragma unroll
  for (int m = 0; m < 4; m++) {
#pragma unroll
    for (int i = 0; i < 4; i++) {
      int row = wr * 64 + m * 16 + rsub + i;
      int gm = mt * 128 + row;
      if (gm < Me) {
        size_t rb = (size_t)(base + gm - ab) * HDIM + nt * 128;
#pragma unroll
        for (int n = 0; n < 4; n++) {
          float hg = accG[m][n][i];
          float hu = accU[m][n][i];
          float a = 0.5f * hg * (1.f + erff(hg * 0.70710678118f)) * hu;
          Abuf[rb + wc * 64 + n * 16 + csub] = f2bf(a);
        }
      }
    }
  }
}

// ---------------- pass 2: Y = A Wd^T, scatter to out ----------------
// shared expert (e==8): plain read-modify-write add (runs last, atomics done)
template<bool WB>
__global__ __launch_bounds__(256, 2) void pass2_kernel(
    const u16* __restrict__ Abuf, const void* __restrict__ WDall,
    const void* __restrict__ SD, const int* __restrict__ tok,
    const float* __restrict__ wtl, const int* __restrict__ cnt,
    const int* __restrict__ offs, float* __restrict__ out, int e0, int ab_off) {
  int nt, mt;
  xcd_map(gridDim.x, gridDim.y, &nt, &mt);
  int e = e0 + blockIdx.z;
  int Me = cnt[e];
  if (mt * 128 >= Me) return;
  int base = offs[e];
  int ab = (ab_off < 0) ? base : ab_off;
  size_t wst = (size_t)HDIM * DDIM;

  __shared__ u16 lA[128 * 64];
  __shared__ u16 lB[128 * 64];

  int tid = threadIdx.x, lane = tid & 63, wv = tid >> 6;
  int wr = wv >> 1, wc = wv & 1;
  int swsrc = ((lane & 7) ^ (lane >> 3)) * 8;

  const u16* ga[4];
#pragma unroll
  for (int q = 0; q < 4; q++) {
    int r = (wv * 4 + q) * 8 + (lane >> 3);
    int slot = base + mt * 128 + r - ab;  // overrun rows feed masked output rows
    ga[q] = Abuf + (size_t)slot * HDIM + swsrc;
  }

  const u16* gb[4];
  const float* pd0 = nullptr;
  int st_r0 = 0, st_chunk = 0, st_win = 0;
  if constexpr (WB) {
    const u16* D = (e == 8) ? (const u16*)SD : (const u16*)WDall + (size_t)e * wst;
#pragma unroll
    for (int q = 0; q < 4; q++) {
      int r = (wv * 4 + q) * 8 + (lane >> 3);
      gb[q] = D + (size_t)(nt * 128 + r) * HDIM + swsrc;
    }
  } else {
    const float* D = (e == 8) ? (const float*)SD : (const float*)WDall + (size_t)e * wst;
    st_r0 = wv * 32 + (lane >> 4);
    int c0 = (lane & 15) * 4;
    st_chunk = c0 >> 3; st_win = c0 & 7;
    pd0 = D + (size_t)(nt * 128 + st_r0) * HDIM + c0;
  }

  f32x4 acc[4][4] = {};

  for (int kt = 0; kt < HDIM / 64; kt++) {
    __syncthreads();
    int ko = kt * 64;
#pragma unroll
    for (int q = 0; q < 4; q++)
      GLOAD16(ga[q] + ko, lA + (wv * 4 + q) * 512);
    if constexpr (WB) {
#pragma unroll
      for (int q = 0; q < 4; q++)
        GLOAD16(gb[q] + ko, lB + (wv * 4 + q) * 512);
    } else {
#pragma unroll
      for (int q = 0; q < 8; q++) {
        int row = st_r0 + q * 4;
        int pc = (((st_chunk ^ (row & 7)) << 3) | st_win);
        float4 vd = *reinterpret_cast<const float4*>(pd0 + ko + q * 4 * HDIM);
        union { u16 h[4]; uint2 w; } od;
        od.h[0] = f2bf(vd.x); od.h[1] = f2bf(vd.y); od.h[2] = f2bf(vd.z); od.h[3] = f2bf(vd.w);
        *reinterpret_cast<uint2*>(lB + row * 64 + pc) = od.w;
      }
    }
    asm volatile("s_waitcnt vmcnt(0)" ::: "memory");
    __syncthreads();

    __builtin_amdgcn_s_setprio(1);
#pragma unroll
    for (int kk = 0; kk < 2; kk++) {
      int kbs = (((kk * 4 + (lane >> 4)) ^ (lane & 7))) * 8;
      short8 af[4];
#pragma unroll
      for (int m = 0; m < 4; m++) {
        int row = wr * 64 + m * 16 + (lane & 15);
        af[m] = *reinterpret_cast<const short8*>(lA + row * 64 + kbs);
      }
#pragma unroll
      for (int n = 0; n < 4; n++) {
        int dr = wc * 64 + n * 16 + (lane & 15);
        short8 bd = *reinterpret_cast<const short8*>(lB + dr * 64 + kbs);
#pragma unroll
        for (int m = 0; m < 4; m++)
          acc[m][n] = __builtin_amdgcn_mfma_f32_16x16x32_bf16(af[m], bd, acc[m][n], 0, 0, 0);
      }
    }
    __builtin_amdgcn_s_setprio(0);
  }

  int rsub = (lane >> 4) * 4, csub = lane & 15;
#pragma unroll
  for (int m = 0; m < 4; m++) {
#pragma unroll
    for (int i = 0; i < 4; i++) {
      int row = wr * 64 + m * 16 + rsub + i;
      int gm = mt * 128 + row;
      if (gm < Me) {
        int t = tok[e * NTOK + gm];
        float w = (e == 8) ? 1.f : wtl[e * NTOK + gm];
        size_t ob = (size_t)t * DDIM + nt * 128;
#pragma unroll
        for (int n = 0; n < 4; n++) {
          float v = w * acc[m][n][i];
          int c = wc * 64 + n * 16 + csub;
          if (e == 8) out[ob + c] = out[ob + c] + v;  // runs last; 1 thread/elem
          else atomicAdd(&out[ob + c], v);
        }
      }
    }
  }
}

// ---------------- host launcher ----------------
extern "C" void kernel_launch(void* const* d_in, const int* in_sizes, int n_in,
                              void* d_out, int out_size, void* d_ws, size_t ws_size,
                              hipStream_t stream) {
  const float* x  = (const float*)d_in[0];
  const float* gw = (const float*)d_in[1];
  const float* wg = (const float*)d_in[2];
  const float* wu = (const float*)d_in[3];
  const float* wd = (const float*)d_in[4];
  const float* sg = (const float*)d_in[5];
  const float* su = (const float*)d_in[6];
  const float* sd = (const float*)d_in[7];
  float* out = (float*)d_out;

  // F >= 327 MB: all-bf16 routed-first schedule (wd/sd overlay dead wg/wu).
  // E >= 223 MB: fp32-staged weights.  D: serial per-expert.
  bool tierF = ws_size >= 327000000ULL;
  bool tierE = !tierF && ws_size >= 223000000ULL;

  char* ws = (char*)d_ws;
  size_t o = 0;
  auto alloc = [&](size_t bytes) -> void* {
    void* p = ws + o;
    o = (o + bytes + 255) & ~(size_t)255;
    return p;
  };
  u16* xbf = (u16*)alloc((size_t)NTOK * DDIM * 2);
  u16 *wgbf = nullptr, *wubf = nullptr, *sgbf = nullptr, *subf = nullptr;
  u16 *wdbf = nullptr, *sdbf = nullptr;
  if (tierF) {
    wgbf = (u16*)alloc((size_t)NE * HDIM * DDIM * 2);
    wubf = (u16*)alloc((size_t)NE * HDIM * DDIM * 2);
    sgbf = (u16*)alloc((size_t)HDIM * DDIM * 2);
    subf = (u16*)alloc((size_t)HDIM * DDIM * 2);
    wdbf = wgbf;                                    // overlay after p1-routed
    sdbf = wgbf + (size_t)NE * DDIM * HDIM;
  }
  size_t abuf_rows = (tierF || tierE) ? ((size_t)2 * NTOK + 128) : ((size_t)NTOK + 128);
  u16* Abuf = (u16*)alloc(abuf_rows * HDIM * 2);
  int*   tok  = (int*)alloc((size_t)NEX * NTOK * 4);
  float* wtl  = (float*)alloc((size_t)NEX * NTOK * 4);
  int*   cnt  = (int*)alloc(64);
  int*   offs = (int*)alloc(64);
  float* Pacc = (float*)alloc(64);
  float* fcnt = (float*)alloc(64);

  hipMemsetAsync(d_out, 0, (size_t)out_size * 4, stream);
  init_kernel<<<1, 64, 0, stream>>>(cnt, Pacc, fcnt);

  if (tierF) {  // pass-1 weight convert (x is fused into router)
    CvtArgs ca;
    long long sizes4[7];
    int nsrc = 0;
    ca.src[nsrc] = wg; ca.dst[nsrc] = wgbf; sizes4[nsrc] = (long long)NE * HDIM * DDIM / 4; nsrc++;
    ca.src[nsrc] = wu; ca.dst[nsrc] = wubf; sizes4[nsrc] = (long long)NE * HDIM * DDIM / 4; nsrc++;
    ca.src[nsrc] = sg; ca.dst[nsrc] = sgbf; sizes4[nsrc] = (long long)HDIM * DDIM / 4; nsrc++;
    ca.src[nsrc] = su; ca.dst[nsrc] = subf; sizes4[nsrc] = (long long)HDIM * DDIM / 4; nsrc++;
    ca.cum[0] = 0;
    for (int i = 0; i < 7; i++)
      ca.cum[i + 1] = ca.cum[i] + (i < nsrc ? sizes4[i] : 0);
    convert_kernel<<<4096, 256, 0, stream>>>(ca);
  }

  router_kernel<<<NTOK / 16, 256, 0, stream>>>(x, gw, tok, wtl, cnt, Pacc, fcnt, xbf);
  finalize_router<<<1, 64, 0, stream>>>(cnt, offs, Pacc, fcnt, out + (out_size - 1));

  if (tierF) {
    // routed-first full-bf16 schedule (round-8 proven)
    pass1_kernel<true><<<dim3(HDIM / 128, NTOK / 128, NE), 256, 0, stream>>>(
        xbf, wgbf, wubf, sgbf, subf, tok, cnt, offs, Abuf, 0, NTOK);
    {  // wg/wu dead -> convert wd,sd into their region
      CvtArgs ca;
      ca.src[0] = wd; ca.dst[0] = wdbf;
      ca.src[1] = sd; ca.dst[1] = sdbf;
      long long s0 = (long long)NE * DDIM * HDIM / 4;
      long long s1 = (long long)DDIM * HDIM / 4;
      ca.cum[0] = 0; ca.cum[1] = s0; ca.cum[2] = s0 + s1;
      for (int i = 3; i <= 7; i++) ca.cum[i] = ca.cum[2];
      convert_kernel<<<4096, 256, 0, stream>>>(ca);
    }
    pass2_kernel<true><<<dim3(DDIM / 128, NTOK / 128, NE), 256, 0, stream>>>(
        Abuf, wdbf, sdbf, tok, wtl, cnt, offs, out, 0, NTOK);
    pass1_kernel<true><<<dim3(HDIM / 128, NTOK / 128, 1), 256, 0, stream>>>(
        xbf, wgbf, wubf, sgbf, subf, tok, cnt, offs, Abuf, 8, 0);
    pass2_kernel<true><<<dim3(DDIM / 128, NTOK / 128, 1), 256, 0, stream>>>(
        Abuf, wdbf, sdbf, tok, wtl, cnt, offs, out, 8, 0);
  } else if (tierE) {
    pass1_kernel<false><<<dim3(HDIM / 128, NTOK / 128, 1), 256, 0, stream>>>(
        xbf, wg, wu, sg, su, tok, cnt, offs, Abuf, 8, 0);
    pass2_kernel<false><<<dim3(DDIM / 128, NTOK / 128, 1), 256, 0, stream>>>(
        Abuf, wd, sd, tok, wtl, cnt, offs, out, 8, 0);
    pass1_kernel<false><<<dim3(HDIM / 128, NTOK / 128, NE), 256, 0, stream>>>(
        xbf, wg, wu, sg, su, tok, cnt, offs, Abuf, 0, NTOK);
    pass2_kernel<false><<<dim3(DDIM / 128, NTOK / 128, NE), 256, 0, stream>>>(
        Abuf, wd, sd, tok, wtl, cnt, offs, out, 0, NTOK);
  } else {
    for (int k = 0; k < NEX; k++) {
      int e = (k == 0) ? 8 : (k - 1);
      pass1_kernel<false><<<dim3(HDIM / 128, NTOK / 128, 1), 256, 0, stream>>>(
          xbf, wg, wu, sg, su, tok, cnt, offs, Abuf, e, -1);
      pass2_kernel<false><<<dim3(DDIM / 128, NTOK / 128, 1), 256, 0, stream>>>(
          Abuf, wd, sd, tok, wtl, cnt, offs, out, e, -1);
    }
  }
}